// Round 1
// baseline (272.275 us; speedup 1.0000x reference)
//
#include <hip/hip_runtime.h>

// SSIM fused kernel for MI355X (gfx950).
// Exploits separability of the Gaussian window (outer(g,g)):
//   per tile: load x1,x2 (+5 halo) -> LDS
//   horizontal 11-tap pass on {x1, x2, x1^2, x2^2, x1*x2} -> LDS
//   vertical 11-tap pass in registers -> mu1, mu2, E[x1^2], E[x2^2], E[x1*x2]
//   per-pixel v, block reduction, one atomicAdd per block.
// finalize kernel: out = 1 - sum/N.

#define TW 32
#define TH 32
#define HALO 5
#define KS 11
#define LW (TW + 2 * HALO) /* 42 */
#define LH (TH + 2 * HALO) /* 42 */
#define IMG 512
#define NIMG 48                    /* 16 * 3 */
#define NPIX (16LL * 3 * 512 * 512)

__global__ __launch_bounds__(256) void ssim_kernel(
    const float* __restrict__ img1,
    const float* __restrict__ img2,
    const float* __restrict__ win,
    float* __restrict__ accum)
{
    __shared__ float sx1[LH][LW + 2];   // +2 pad: keep 4B banks happy
    __shared__ float sx2[LH][LW + 2];
    __shared__ float h1 [LH][TW + 1];
    __shared__ float h2 [LH][TW + 1];
    __shared__ float h11[LH][TW + 1];
    __shared__ float h22[LH][TW + 1];
    __shared__ float h12[LH][TW + 1];
    __shared__ float sg[KS];
    __shared__ float red[4];

    const int tid = threadIdx.x;
    const int tx0 = blockIdx.x * TW;
    const int ty0 = blockIdx.y * TH;
    const int z   = blockIdx.z;

    // Recover the 1D gaussian from the 2D window: w2d[5][j] = g5*g[j], g5 = sqrt(w2d[5][5]).
    if (tid < KS) {
        float c = win[5 * KS + 5];
        sg[tid] = win[5 * KS + tid] * rsqrtf(c);
    }

    const float* __restrict__ p1 = img1 + (size_t)z * IMG * IMG;
    const float* __restrict__ p2 = img2 + (size_t)z * IMG * IMG;

    // Stage tile + halo, zero padding outside the image.
    for (int idx = tid; idx < LH * LW; idx += 256) {
        int r = idx / LW, c = idx % LW;
        int gr = ty0 - HALO + r;
        int gc = tx0 - HALO + c;
        float a = 0.f, b = 0.f;
        if ((unsigned)gr < IMG && (unsigned)gc < IMG) {
            a = p1[gr * IMG + gc];
            b = p2[gr * IMG + gc];
        }
        sx1[r][c] = a;
        sx2[r][c] = b;
    }
    __syncthreads();

    float g[KS];
    #pragma unroll
    for (int j = 0; j < KS; ++j) g[j] = sg[j];

    // Horizontal pass: 42 rows x 32 cols, 5 quantities.
    for (int idx = tid; idx < LH * TW; idx += 256) {
        int r = idx / TW, c = idx % TW;
        float a1 = 0.f, a2 = 0.f, a11 = 0.f, a22 = 0.f, a12 = 0.f;
        #pragma unroll
        for (int j = 0; j < KS; ++j) {
            float a = sx1[r][c + j];
            float b = sx2[r][c + j];
            float w = g[j];
            a1  = fmaf(w, a, a1);
            a2  = fmaf(w, b, a2);
            a11 = fmaf(w, a * a, a11);
            a22 = fmaf(w, b * b, a22);
            a12 = fmaf(w, a * b, a12);
        }
        h1 [r][c] = a1;
        h2 [r][c] = a2;
        h11[r][c] = a11;
        h22[r][c] = a22;
        h12[r][c] = a12;
    }
    __syncthreads();

    const float C1 = 1e-4f;  // 0.01^2
    const float C2 = 9e-4f;  // 0.03^2
    float vsum = 0.f;

    // Vertical pass + SSIM map, 32x32 outputs (4 per thread).
    for (int idx = tid; idx < TH * TW; idx += 256) {
        int r = idx / TW, c = idx % TW;
        float mu1 = 0.f, mu2 = 0.f, s11 = 0.f, s22 = 0.f, s12 = 0.f;
        #pragma unroll
        for (int i = 0; i < KS; ++i) {
            float w = g[i];
            mu1 = fmaf(w, h1 [r + i][c], mu1);
            mu2 = fmaf(w, h2 [r + i][c], mu2);
            s11 = fmaf(w, h11[r + i][c], s11);
            s22 = fmaf(w, h22[r + i][c], s22);
            s12 = fmaf(w, h12[r + i][c], s12);
        }
        float mu1s = mu1 * mu1;
        float mu2s = mu2 * mu2;
        float mu12 = mu1 * mu2;
        float sig1 = s11 - mu1s;
        float sig2 = s22 - mu2s;
        float sg12 = s12 - mu12;
        float num = (2.f * mu12 + C1) * (2.f * sg12 + C2);
        float den = (mu1s + mu2s + C1) * (sig1 + sig2 + C2);
        vsum += num / den;
    }

    // Reduce: wave shuffle (width 64), then 4 partials in LDS, one atomic per block.
    #pragma unroll
    for (int off = 32; off > 0; off >>= 1)
        vsum += __shfl_down(vsum, off, 64);
    int lane = tid & 63, wv = tid >> 6;
    if (lane == 0) red[wv] = vsum;
    __syncthreads();
    if (tid == 0) {
        float s = red[0] + red[1] + red[2] + red[3];
        atomicAdd(accum, s);
    }
}

__global__ void finalize_kernel(const float* __restrict__ accum,
                                float* __restrict__ out)
{
    out[0] = 1.0f - accum[0] / (float)NPIX;
}

extern "C" void kernel_launch(void* const* d_in, const int* in_sizes, int n_in,
                              void* d_out, int out_size, void* d_ws, size_t ws_size,
                              hipStream_t stream) {
    const float* img1 = (const float*)d_in[0];
    const float* img2 = (const float*)d_in[1];
    const float* win  = (const float*)d_in[2];
    float* out   = (float*)d_out;
    float* accum = (float*)d_ws;

    // d_ws is re-poisoned (0xAA) before every timed launch — zero our accumulator.
    hipMemsetAsync(accum, 0, sizeof(float), stream);

    dim3 grid(IMG / TW, IMG / TH, NIMG);
    ssim_kernel<<<grid, dim3(256), 0, stream>>>(img1, img2, win, accum);
    finalize_kernel<<<1, 1, 0, stream>>>(accum, out);
}

// Round 2
// 170.940 us; speedup vs baseline: 1.5928x; 1.5928x over previous
//
#include <hip/hip_runtime.h>

// SSIM fused, v2: vertical-pass-first separable conv, register-blocked.
//   v-pass: read raw pixels straight from global (coalesced, L1/L2-cached halo),
//           form 4 quantities {x1, x2, x1^2+x2^2, x1*x2}, 11-tap vertical conv,
//           8 output rows per thread (sliding accumulators) -> LDS v-buffer.
//   h-pass: 11-tap horizontal conv from LDS via aligned ds_read_b128,
//           4 pixels per thread, SSIM map, block reduce -> per-block partial.
//   finalize: reduce 12288 partials, out = 1 - sum/N.
// LDS = 22.6 KB -> ~7 blocks/CU (vs 43 KB / 3 blocks in v1).
// Only 4 filtered quantities needed: sig1+sig2 = E[x1^2+x2^2] - mu1^2 - mu2^2.

#define IMG 512
#define TW 32
#define TH 32
#define PITCH 44            /* 42 cols used; 44 keeps rows 176 B = 16B-aligned */
#define NPIX (16LL * 3 * 512 * 512)
#define NBLK (16 * 16 * 48) /* 12288 blocks -> 48 KB of partials in d_ws */

__device__ __forceinline__ float uniform_f(float x) {
    return __int_as_float(__builtin_amdgcn_readfirstlane(__float_as_int(x)));
}

__global__ __launch_bounds__(256, 6) void ssim_kernel(
    const float* __restrict__ img1,
    const float* __restrict__ img2,
    const float* __restrict__ win,
    float* __restrict__ partial)
{
    __shared__ float vbuf[4][TH][PITCH];  // 22528 B
    __shared__ float sg[12];
    __shared__ float red[4];

    const int tid = threadIdx.x;
    const int tx0 = blockIdx.x * TW;
    const int ty0 = blockIdx.y * TH;
    const int z   = blockIdx.z;

    // 1D gaussian from 2D window: w2d[5][j] = g5*g[j], g5 = sqrt(w2d[5][5]).
    if (tid < 11) sg[tid] = win[55 + tid] * rsqrtf(win[60]);
    __syncthreads();

    float g[11];
    #pragma unroll
    for (int i = 0; i < 11; ++i) g[i] = uniform_f(sg[i]);  // force SGPR

    const size_t zoff = (size_t)z * IMG * IMG;
    const float* __restrict__ p1 = img1 + zoff;
    const float* __restrict__ p2 = img2 + zoff;

    // ---- vertical pass: 42 cols x 4 rowgroups(8 rows) = 168 work items ----
    if (tid < 168) {
        const int col = tid % 42;
        const int rg  = tid / 42;
        const int r0  = rg * 8;
        const int gc  = tx0 - 5 + col;
        const bool cok = (unsigned)gc < IMG;

        float acc[8][4];
        #pragma unroll
        for (int k = 0; k < 8; ++k)
            #pragma unroll
            for (int q = 0; q < 4; ++q) acc[k][q] = 0.f;

        #pragma unroll
        for (int i = 0; i < 18; ++i) {
            const int gr = ty0 - 5 + r0 + i;
            float a = 0.f, b = 0.f;
            if (cok && (unsigned)gr < IMG) {
                a = p1[(size_t)gr * IMG + gc];
                b = p2[(size_t)gr * IMG + gc];
            }
            const float q2 = fmaf(a, a, b * b);  // x1^2 + x2^2
            const float q3 = a * b;              // x1*x2
            #pragma unroll
            for (int k = 0; k < 8; ++k) {
                const int t = i - k;
                if (t >= 0 && t <= 10) {
                    const float w = g[t];
                    acc[k][0] = fmaf(w, a,  acc[k][0]);
                    acc[k][1] = fmaf(w, b,  acc[k][1]);
                    acc[k][2] = fmaf(w, q2, acc[k][2]);
                    acc[k][3] = fmaf(w, q3, acc[k][3]);
                }
            }
        }
        #pragma unroll
        for (int k = 0; k < 8; ++k) {
            #pragma unroll
            for (int q = 0; q < 4; ++q)
                vbuf[q][r0 + k][col] = acc[k][q];
        }
    }
    __syncthreads();

    // ---- horizontal pass: 32 rows x 8 colgroups(4 px) = 256 items ----
    const int cg  = tid & 7;
    const int row = tid >> 3;
    const int c0  = cg * 4;

    float mu1[4], mu2[4], es[4], ex[4];

    auto hconv = [&](int q, float out[4]) {
        const float4* rp = (const float4*)&vbuf[q][row][c0];  // 16B-aligned
        const float4 A = rp[0], B = rp[1], C = rp[2], D = rp[3];
        const float v[16] = {A.x, A.y, A.z, A.w, B.x, B.y, B.z, B.w,
                             C.x, C.y, C.z, C.w, D.x, D.y, D.z, D.w};
        #pragma unroll
        for (int px = 0; px < 4; ++px) {
            float s = 0.f;
            #pragma unroll
            for (int t = 0; t < 11; ++t) s = fmaf(g[t], v[px + t], s);
            out[px] = s;
        }
    };
    hconv(0, mu1);
    hconv(1, mu2);
    hconv(2, es);
    hconv(3, ex);

    const float C1c = 1e-4f;  // 0.01^2
    const float C2c = 9e-4f;  // 0.03^2
    float vsum = 0.f;
    #pragma unroll
    for (int px = 0; px < 4; ++px) {
        const float m1 = mu1[px], m2 = mu2[px];
        const float m1s = m1 * m1, m2s = m2 * m2, m12 = m1 * m2;
        const float sig = es[px] - m1s - m2s;   // sig1_sq + sig2_sq
        const float s12 = ex[px] - m12;
        const float num = (2.f * m12 + C1c) * (2.f * s12 + C2c);
        const float den = (m1s + m2s + C1c) * (sig + C2c);
        vsum += num * __builtin_amdgcn_rcpf(den);
    }

    // ---- block reduction -> one partial per block (no atomics, no memset) ----
    #pragma unroll
    for (int off = 32; off > 0; off >>= 1)
        vsum += __shfl_down(vsum, off, 64);
    if ((tid & 63) == 0) red[tid >> 6] = vsum;
    __syncthreads();
    if (tid == 0) {
        const int bidx = (blockIdx.z * gridDim.y + blockIdx.y) * gridDim.x + blockIdx.x;
        partial[bidx] = red[0] + red[1] + red[2] + red[3];
    }
}

__global__ __launch_bounds__(256) void finalize_kernel(
    const float* __restrict__ partial, float* __restrict__ out)
{
    __shared__ float red[4];
    float s = 0.f;
    for (int i = threadIdx.x; i < NBLK; i += 256) s += partial[i];
    #pragma unroll
    for (int off = 32; off > 0; off >>= 1)
        s += __shfl_down(s, off, 64);
    if ((threadIdx.x & 63) == 0) red[threadIdx.x >> 6] = s;
    __syncthreads();
    if (threadIdx.x == 0)
        out[0] = 1.0f - (red[0] + red[1] + red[2] + red[3]) / (float)NPIX;
}

extern "C" void kernel_launch(void* const* d_in, const int* in_sizes, int n_in,
                              void* d_out, int out_size, void* d_ws, size_t ws_size,
                              hipStream_t stream) {
    const float* img1 = (const float*)d_in[0];
    const float* img2 = (const float*)d_in[1];
    const float* win  = (const float*)d_in[2];
    float* partial = (float*)d_ws;  // NBLK floats = 48 KB; every slot written each call

    dim3 grid(IMG / TW, IMG / TH, 48);
    ssim_kernel<<<grid, dim3(256), 0, stream>>>(img1, img2, win, partial);
    finalize_kernel<<<1, dim3(256), 0, stream>>>(partial, (float*)d_out);
}

// Round 3
// 153.487 us; speedup vs baseline: 1.7739x; 1.1137x over previous
//
#include <hip/hip_runtime.h>

// SSIM fused, v3: packed-fp32 (v_pk_fma_f32) separable conv + interior/edge split.
//   Quantities paired for VOP3P: A = {mu1-partial, mu2-partial}, B = {E[x1^2+x2^2]-p, E[x1*x2]-p}.
//   v-pass: global loads (unconditional on interior blocks), 11-tap vertical conv via
//           packed FMA, 8 output rows/thread -> two v2f LDS buffers.
//   h-pass: 11-tap horizontal conv via packed FMA from aligned float4 LDS reads,
//           4 px/thread, SSIM map, block reduce -> per-block partial.
//   finalize: float4 reduce of 12288 partials, out = 1 - sum/N.

#define IMG 512
#define TW 32
#define TH 32
#define PP 46               /* v2f pitch: 42 used; 46 keeps rows 368 B = 16B-aligned */
#define NPIX (16LL * 3 * 512 * 512)
#define NBLK (16 * 16 * 48)

typedef float v2f __attribute__((ext_vector_type(2)));

__device__ __forceinline__ float uniform_f(float x) {
    return __int_as_float(__builtin_amdgcn_readfirstlane(__float_as_int(x)));
}

template <bool EDGE>
__device__ __forceinline__ void ssim_tile(
    const float* __restrict__ p1, const float* __restrict__ p2,
    const float* g, int tx0, int ty0, int tid,
    v2f (*vbufA)[PP], v2f (*vbufB)[PP], float* red, float* partial, int bidx)
{
    // ---- vertical pass: 42 cols x 4 rowgroups(8 rows) = 168 threads ----
    if (tid < 168) {
        const int col = tid % 42;
        const int rg  = tid / 42;
        const int r0  = rg * 8;
        const int gc  = tx0 - 5 + col;
        const bool cok = EDGE ? ((unsigned)gc < IMG) : true;

        v2f accA[8], accB[8];
        #pragma unroll
        for (int k = 0; k < 8; ++k) { accA[k] = (v2f)0.f; accB[k] = (v2f)0.f; }

        const size_t base = (size_t)(ty0 - 5) * IMG + gc;
        #pragma unroll
        for (int i = 0; i < 18; ++i) {
            float a, b;
            if (EDGE) {
                const int gr = ty0 - 5 + r0 + i;
                a = b = 0.f;
                if (cok && (unsigned)gr < IMG) {
                    a = p1[(size_t)gr * IMG + gc];
                    b = p2[(size_t)gr * IMG + gc];
                }
            } else {
                const size_t off = base + (size_t)(r0 + i) * IMG;
                a = p1[off];
                b = p2[off];
            }
            v2f pA, pB;
            pA.x = a; pA.y = b;
            pB.x = fmaf(a, a, b * b);
            pB.y = a * b;
            #pragma unroll
            for (int k = 0; k < 8; ++k) {
                const int t = i - k;
                if (t >= 0 && t <= 10) {
                    v2f w2; w2.x = g[t]; w2.y = g[t];
                    accA[k] = __builtin_elementwise_fma(w2, pA, accA[k]);
                    accB[k] = __builtin_elementwise_fma(w2, pB, accB[k]);
                }
            }
        }
        #pragma unroll
        for (int k = 0; k < 8; ++k) {
            vbufA[r0 + k][col] = accA[k];
            vbufB[r0 + k][col] = accB[k];
        }
    }
    __syncthreads();

    // ---- horizontal pass: 32 rows x 8 colgroups(4 px) = 256 threads ----
    const int cg  = tid & 7;
    const int row = tid >> 3;
    const int c0  = cg * 4;

    v2f va[16], vb[16];
    {
        const float4* rA = (const float4*)&vbufA[row][c0];  // 32B-aligned
        const float4* rB = (const float4*)&vbufB[row][c0];
        #pragma unroll
        for (int m = 0; m < 8; ++m) {
            float4 t = rA[m];
            va[2 * m].x = t.x; va[2 * m].y = t.y;
            va[2 * m + 1].x = t.z; va[2 * m + 1].y = t.w;
            t = rB[m];
            vb[2 * m].x = t.x; vb[2 * m].y = t.y;
            vb[2 * m + 1].x = t.z; vb[2 * m + 1].y = t.w;
        }
    }

    const float C1c = 1e-4f;
    const float C2c = 9e-4f;
    float vsum = 0.f;
    #pragma unroll
    for (int px = 0; px < 4; ++px) {
        v2f sA = (v2f)0.f, sB = (v2f)0.f;
        #pragma unroll
        for (int t = 0; t < 11; ++t) {
            v2f w2; w2.x = g[t]; w2.y = g[t];
            sA = __builtin_elementwise_fma(w2, va[px + t], sA);
            sB = __builtin_elementwise_fma(w2, vb[px + t], sB);
        }
        const float m1 = sA.x, m2 = sA.y, es = sB.x, ex = sB.y;
        const float m1s = m1 * m1, m2s = m2 * m2, m12 = m1 * m2;
        const float sig = es - m1s - m2s;   // sig1_sq + sig2_sq
        const float s12 = ex - m12;
        const float num = (2.f * m12 + C1c) * (2.f * s12 + C2c);
        const float den = (m1s + m2s + C1c) * (sig + C2c);
        vsum += num * __builtin_amdgcn_rcpf(den);
    }

    #pragma unroll
    for (int off = 32; off > 0; off >>= 1)
        vsum += __shfl_down(vsum, off, 64);
    if ((tid & 63) == 0) red[tid >> 6] = vsum;
    __syncthreads();
    if (tid == 0)
        partial[bidx] = red[0] + red[1] + red[2] + red[3];
}

__global__ __launch_bounds__(256, 6) void ssim_kernel(
    const float* __restrict__ img1,
    const float* __restrict__ img2,
    const float* __restrict__ win,
    float* __restrict__ partial)
{
    __shared__ v2f vbufA[TH][PP];   // 11776 B
    __shared__ v2f vbufB[TH][PP];   // 11776 B
    __shared__ float sg[12];
    __shared__ float red[4];

    const int tid = threadIdx.x;
    const int bx = blockIdx.x, by = blockIdx.y, z = blockIdx.z;
    const int tx0 = bx * TW, ty0 = by * TH;

    if (tid < 11) sg[tid] = win[55 + tid] * rsqrtf(win[60]);
    __syncthreads();

    float g[11];
    #pragma unroll
    for (int i = 0; i < 11; ++i) g[i] = uniform_f(sg[i]);

    const size_t zoff = (size_t)z * IMG * IMG;
    const float* p1 = img1 + zoff;
    const float* p2 = img2 + zoff;
    const int bidx = (z * (int)gridDim.y + by) * (int)gridDim.x + bx;

    const bool interior = (bx > 0) & (bx < (int)gridDim.x - 1) &
                          (by > 0) & (by < (int)gridDim.y - 1);
    if (interior)
        ssim_tile<false>(p1, p2, g, tx0, ty0, tid, vbufA, vbufB, red, partial, bidx);
    else
        ssim_tile<true>(p1, p2, g, tx0, ty0, tid, vbufA, vbufB, red, partial, bidx);
}

__global__ __launch_bounds__(256) void finalize_kernel(
    const float* __restrict__ partial, float* __restrict__ out)
{
    __shared__ float red[4];
    const float4* p4 = (const float4*)partial;
    float s = 0.f;
    for (int i = threadIdx.x; i < NBLK / 4; i += 256) {
        float4 t = p4[i];
        s += (t.x + t.y) + (t.z + t.w);
    }
    #pragma unroll
    for (int off = 32; off > 0; off >>= 1)
        s += __shfl_down(s, off, 64);
    if ((threadIdx.x & 63) == 0) red[threadIdx.x >> 6] = s;
    __syncthreads();
    if (threadIdx.x == 0)
        out[0] = 1.0f - (red[0] + red[1] + red[2] + red[3]) / (float)NPIX;
}

extern "C" void kernel_launch(void* const* d_in, const int* in_sizes, int n_in,
                              void* d_out, int out_size, void* d_ws, size_t ws_size,
                              hipStream_t stream) {
    const float* img1 = (const float*)d_in[0];
    const float* img2 = (const float*)d_in[1];
    const float* win  = (const float*)d_in[2];
    float* partial = (float*)d_ws;  // NBLK floats; every slot written each call

    dim3 grid(IMG / TW, IMG / TH, 48);
    ssim_kernel<<<grid, dim3(256), 0, stream>>>(img1, img2, win, partial);
    finalize_kernel<<<1, dim3(256), 0, stream>>>(partial, (float*)d_out);
}